// Round 1
// baseline (423.210 us; speedup 1.0000x reference)
//
#include <hip/hip_runtime.h>
#include <cstdint>
#include <cstddef>

// GeoRoPESatelliteAttnProcessor — bf16 MFMA implementation.
// Pipeline: transpose weights -> pf1 -> pf2 GEMM -> gate(+loss parts)
//           -> sat LN -> KV GEMM -> Q GEMM -> RoPE(Q,K) -> V transpose -> attention -> loss.
// ws budget ~51 MB (regions aliased across pipeline phases).

#define B_    4
#define SQ_   4096
#define SK_   1024
#define HID_  640
#define SATD_ 768
#define NH_   10
#define HD_   64

typedef __bf16 bf16_t;
typedef __bf16 bf16x4 __attribute__((ext_vector_type(4)));
typedef __bf16 bf16x8 __attribute__((ext_vector_type(8)));
typedef float  f32x4  __attribute__((ext_vector_type(4)));
typedef unsigned short u16x8 __attribute__((ext_vector_type(8)));

static __device__ __forceinline__ unsigned short f2u(float f) {
  bf16_t b = (bf16_t)f;                      // RNE f32->bf16
  return __builtin_bit_cast(unsigned short, b);
}
static __device__ __forceinline__ float u2f(unsigned short u) {
  return (float)__builtin_bit_cast(bf16_t, u);
}
static __device__ __forceinline__ f32x4 mfma16(bf16x8 a, bf16x8 b, f32x4 c) {
  return __builtin_amdgcn_mfma_f32_16x16x32_bf16(a, b, c, 0, 0, 0);
}

// ---------------- weight prep ----------------
__global__ void k_transpose_w(const float* __restrict__ W, unsigned short* __restrict__ WT,
                              int K, int N) {
  int i = blockIdx.x * 256 + threadIdx.x;   // over N*K
  if (i >= N * K) return;
  int n = i / K, k = i - n * K;
  WT[i] = f2u(W[(size_t)k * N + n]);
}

__global__ void k_concat_bias(const float* __restrict__ bk, const float* __restrict__ bv,
                              float* __restrict__ out) {
  int i = blockIdx.x * 256 + threadIdx.x;
  if (i < HID_) out[i] = bk[i];
  else if (i < 2 * HID_) out[i] = bv[i - HID_];
}

// ---------------- sat LayerNorm -> bf16 ----------------
__global__ __launch_bounds__(256) void k_satln(const float* __restrict__ x,
                                               const float* __restrict__ g,
                                               const float* __restrict__ bta,
                                               unsigned short* __restrict__ out) {
  int r = blockIdx.x;                // 0..4095
  const float* xr = x + (size_t)r * SATD_;
  int t = threadIdx.x;
  float v0 = xr[t], v1 = xr[t + 256], v2 = xr[t + 512];
  float s = v0 + v1 + v2;
  float ss = v0 * v0 + v1 * v1 + v2 * v2;
  __shared__ float sb[8];
  for (int o = 32; o; o >>= 1) { s += __shfl_xor(s, o); ss += __shfl_xor(ss, o); }
  if ((t & 63) == 0) { sb[t >> 6] = s; sb[4 + (t >> 6)] = ss; }
  __syncthreads();
  s  = sb[0] + sb[1] + sb[2] + sb[3];
  ss = sb[4] + sb[5] + sb[6] + sb[7];
  float m = s * (1.f / SATD_);
  float rstd = rsqrtf(ss * (1.f / SATD_) - m * m + 1e-5f);
  unsigned short* orow = out + (size_t)r * SATD_;
  orow[t]       = f2u((v0 - m) * rstd * g[t]       + bta[t]);
  orow[t + 256] = f2u((v1 - m) * rstd * g[t + 256] + bta[t + 256]);
  orow[t + 512] = f2u((v2 - m) * rstd * g[t + 512] + bta[t + 512]);
}

// ---------------- pf1 = silu(plucker @ Wp1 + bp1) ----------------
__global__ void k_pf1(const float* __restrict__ plk, const float* __restrict__ W,
                      const float* __restrict__ bias, unsigned short* __restrict__ out) {
  int i = blockIdx.x * 256 + threadIdx.x;       // over 16384*640
  int r = i / HID_, c = i - r * HID_;
  const float* p = plk + (size_t)r * 6;
  float a = bias[c];
#pragma unroll
  for (int j = 0; j < 6; j++) a += p[j] * W[j * HID_ + c];
  out[i] = f2u(a / (1.f + __expf(-a)));
}

// ---------------- GEMM: C[M,N](bf16) = A[M,K] @ BT[N,K]^T + bias ----------------
template <bool A_IS_F32>
__global__ __launch_bounds__(256) void k_gemm(const void* __restrict__ Ap,
                                              const unsigned short* __restrict__ BT,
                                              const float* __restrict__ bias,
                                              unsigned short* __restrict__ C,
                                              int M, int N, int K) {
  __shared__ unsigned short As[128 * 40];   // stride 40 elems (80B): 2-way-max banks, 16B aligned
  __shared__ unsigned short Bs[128 * 40];
  const int bm = blockIdx.x * 128, bn = blockIdx.y * 128;
  const int t = threadIdx.x;
  const int lane = t & 63, wv = t >> 6;
  const int lc = lane & 15, quad = lane >> 4;
  const int wm = (wv >> 1) * 64, wn = (wv & 1) * 64;
  f32x4 acc[4][4];
  f32x4 zero = {0.f, 0.f, 0.f, 0.f};
#pragma unroll
  for (int i = 0; i < 4; i++)
#pragma unroll
    for (int j = 0; j < 4; j++) acc[i][j] = zero;
  const int arow = t >> 2, acol = (t & 3) * 8;

  for (int k0 = 0; k0 < K; k0 += 32) {
    __syncthreads();
#pragma unroll
    for (int i = 0; i < 2; i++) {
      int row = arow + i * 64;
      if constexpr (A_IS_F32) {
        const float* ap = (const float*)Ap + (size_t)(bm + row) * K + k0 + acol;
        float4 a0 = *(const float4*)ap;
        float4 a1 = *(const float4*)(ap + 4);
        u16x8 u = { f2u(a0.x), f2u(a0.y), f2u(a0.z), f2u(a0.w),
                    f2u(a1.x), f2u(a1.y), f2u(a1.z), f2u(a1.w) };
        *(u16x8*)&As[row * 40 + acol] = u;
      } else {
        const unsigned short* ap = (const unsigned short*)Ap + (size_t)(bm + row) * K + k0 + acol;
        *(u16x8*)&As[row * 40 + acol] = *(const u16x8*)ap;
      }
      const unsigned short* bp = BT + (size_t)(bn + row) * K + k0 + acol;
      *(u16x8*)&Bs[row * 40 + acol] = *(const u16x8*)bp;
    }
    __syncthreads();
    bf16x8 af[4], bfr[4];
#pragma unroll
    for (int mt = 0; mt < 4; mt++) af[mt]  = *(const bf16x8*)&As[(wm + mt * 16 + lc) * 40 + quad * 8];
#pragma unroll
    for (int nt = 0; nt < 4; nt++) bfr[nt] = *(const bf16x8*)&Bs[(wn + nt * 16 + lc) * 40 + quad * 8];
#pragma unroll
    for (int mt = 0; mt < 4; mt++)
#pragma unroll
      for (int nt = 0; nt < 4; nt++) acc[mt][nt] = mfma16(af[mt], bfr[nt], acc[mt][nt]);
  }
  // epilogue: C row = quad*4+r (verified C/D layout), col = lane&15
#pragma unroll
  for (int mt = 0; mt < 4; mt++) {
    int row = bm + wm + mt * 16 + quad * 4;
#pragma unroll
    for (int nt = 0; nt < 4; nt++) {
      int col = bn + wn + nt * 16 + lc;
      float bsv = bias[col];
#pragma unroll
      for (int r = 0; r < 4; r++)
        C[(size_t)(row + r) * N + col] = f2u(acc[mt][nt][r] + bsv);
    }
  }
}

// ---------------- RoPE in-place (bf16), optional 1/sqrt(D) fold into Q ----------------
__global__ void k_rope(unsigned short* __restrict__ buf, const float* __restrict__ xy,
                       int rows, int rowstride, float qscale) {
  int i = blockIdx.x * 256 + threadIdx.x;   // rows * NH * 32
  int d = i & 31;
  int rh = i >> 5;
  int h = rh % NH_;
  int r = rh / NH_;
  if (r >= rows) return;
  float coord = (d < 16) ? xy[(size_t)r * 2] : xy[(size_t)r * 2 + 1];
  int j = d & 15;
  float inv = __expf(-(float)j * (9.210340371976184f / 16.f));   // 10000^(-j/16)
  float ang = coord * inv;
  float cs = __cosf(ang), sn = __sinf(ang);
  size_t base = (size_t)r * rowstride + h * HD_ + d;
  float t1 = u2f(buf[base]), t2 = u2f(buf[base + 32]);
  buf[base]      = f2u((t1 * cs - t2 * sn) * qscale);
  buf[base + 32] = f2u((t1 * sn + t2 * cs) * qscale);
}

// ---------------- gate = sigmoid(LN(hidden + pf2) @ Wg + bg) ----------------
__global__ __launch_bounds__(256) void k_gate(const float* __restrict__ hid,
                                              const unsigned short* __restrict__ pf2,
                                              const float* __restrict__ g,
                                              const float* __restrict__ be,
                                              const float* __restrict__ Wg,
                                              const float* __restrict__ bg,
                                              const float* __restrict__ vm,
                                              float* __restrict__ gate_buf,
                                              float* __restrict__ lg_buf) {
  int r = blockIdx.x;    // 0..16383
  const float* hr = hid + (size_t)r * HID_;
  const unsigned short* pr = pf2 + (size_t)r * HID_;
  int t = threadIdx.x;
  __shared__ float xb[HID_];
  __shared__ float sb[8];
  float s = 0.f, ss = 0.f;
  for (int c = t; c < HID_; c += 256) {
    float x = hr[c] + u2f(pr[c]);
    xb[c] = x; s += x; ss += x * x;
  }
  for (int o = 32; o; o >>= 1) { s += __shfl_xor(s, o); ss += __shfl_xor(ss, o); }
  if ((t & 63) == 0) { sb[t >> 6] = s; sb[4 + (t >> 6)] = ss; }
  __syncthreads();
  s  = sb[0] + sb[1] + sb[2] + sb[3];
  ss = sb[4] + sb[5] + sb[6] + sb[7];
  float m = s * (1.f / HID_);
  float rstd = rsqrtf(ss * (1.f / HID_) - m * m + 1e-5f);
  float dacc = 0.f;
  for (int c = t; c < HID_; c += 256)
    dacc += ((xb[c] - m) * rstd * g[c] + be[c]) * Wg[c];
  for (int o = 32; o; o >>= 1) dacc += __shfl_xor(dacc, o);
  __syncthreads();
  if ((t & 63) == 0) sb[t >> 6] = dacc;
  __syncthreads();
  if (t == 0) {
    float dsum = sb[0] + sb[1] + sb[2] + sb[3] + bg[0];
    float gate = 1.f / (1.f + __expf(-dsum));
    float v = vm[r];
    gate_buf[r] = (v > 0.5f) ? gate : 0.f;   // masked gate for attention epilogue
    lg_buf[r]   = (v > 0.5f) ? 0.f : gate;   // gate on invalid rows, for loss
  }
}

// ---------------- V transpose: kv_lin[:,640:1280] -> vT[b][hid][sk] ----------------
__global__ __launch_bounds__(256) void k_transpose_v(const unsigned short* __restrict__ kv_lin,
                                                     unsigned short* __restrict__ vT) {
  __shared__ unsigned short tile[64 * 65];    // [d][key], +1 pad
  const int b = blockIdx.z, kt0 = blockIdx.x * 64, d0 = blockIdx.y * 64;
  const int t = threadIdx.x;
  const int row = t >> 3, c8 = (t & 7) * 8;
#pragma unroll
  for (int i = 0; i < 2; i++) {
    int kk = row + i * 32;
    u16x8 v = *(const u16x8*)(kv_lin + (size_t)(b * SK_ + kt0 + kk) * (2 * HID_) + HID_ + d0 + c8);
#pragma unroll
    for (int u = 0; u < 8; u++) tile[(c8 + u) * 65 + kk] = v[u];
  }
  __syncthreads();
#pragma unroll
  for (int i = 0; i < 2; i++) {
    int dd = row + i * 32;
    u16x8 o;
#pragma unroll
    for (int u = 0; u < 8; u++) o[u] = tile[dd * 65 + c8 + u];
    *(u16x8*)(vT + ((size_t)b * HID_ + d0 + dd) * SK_ + kt0 + c8) = o;
  }
}

// ---------------- attention (flash-style, transposed S^T = K Q^T) ----------------
__global__ __launch_bounds__(256) void k_attn(const unsigned short* __restrict__ q_lin,
                                              const unsigned short* __restrict__ kv_lin,
                                              const unsigned short* __restrict__ vT,
                                              const float* __restrict__ gate_buf,
                                              float* __restrict__ out) {
  __shared__ unsigned short Ks[64 * 72];      // [key][d], stride 72
  __shared__ unsigned short Vt[64 * 72];      // [d][key], stride 72
  __shared__ unsigned short Pt[4][16 * 72];   // per wave: [q][key], stride 72
  const int qb = blockIdx.x * 64;
  const int bh = blockIdx.y;
  const int b = bh / NH_, h = bh - b * NH_;
  const int t = threadIdx.x, wv = t >> 6, lane = t & 63;
  const int lc = lane & 15, quad = lane >> 4;

  // Q B-operand frags: lane holds Q[q=lc][dim=quad*8+j (+32)] (q pre-scaled by 1/8)
  const unsigned short* qrow = q_lin + (size_t)(b * SQ_ + qb + wv * 16 + lc) * HID_ + h * HD_;
  bf16x8 qf0 = *(const bf16x8*)(qrow + quad * 8);
  bf16x8 qf1 = *(const bf16x8*)(qrow + 32 + quad * 8);

  f32x4 O[4];
  f32x4 zero = {0.f, 0.f, 0.f, 0.f};
#pragma unroll
  for (int dt = 0; dt < 4; dt++) O[dt] = zero;
  float m_run = -__builtin_inff(), l_run = 0.f;

  const unsigned short* Kg = kv_lin + (size_t)b * SK_ * (2 * HID_) + h * HD_;
  const unsigned short* Vg = vT + ((size_t)b * HID_ + h * HD_) * SK_;
  const int srow = t >> 3, scol = (t & 7) * 8;

  for (int kc = 0; kc < SK_; kc += 64) {
    __syncthreads();
#pragma unroll
    for (int i = 0; i < 2; i++) {
      int row = srow + i * 32;
      *(u16x8*)&Ks[row * 72 + scol] = *(const u16x8*)(Kg + (size_t)(kc + row) * (2 * HID_) + scol);
      *(u16x8*)&Vt[row * 72 + scol] = *(const u16x8*)(Vg + (size_t)row * SK_ + kc + scol);
    }
    __syncthreads();

    // S^T tiles: ST[kt] holds rows key = kt*16 + quad*4 + reg, col q = lc
    f32x4 ST[4];
#pragma unroll
    for (int kt = 0; kt < 4; kt++) {
      f32x4 sacc = zero;
      bf16x8 ka0 = *(const bf16x8*)&Ks[(kt * 16 + lc) * 72 + quad * 8];
      bf16x8 ka1 = *(const bf16x8*)&Ks[(kt * 16 + lc) * 72 + 32 + quad * 8];
      sacc = mfma16(ka0, qf0, sacc);
      sacc = mfma16(ka1, qf1, sacc);
      ST[kt] = sacc;
    }

    // online softmax: per-lane scalar stats (one q per lane), reduce across quads
    float mloc = -__builtin_inff();
#pragma unroll
    for (int kt = 0; kt < 4; kt++)
#pragma unroll
      for (int r = 0; r < 4; r++) mloc = fmaxf(mloc, ST[kt][r]);
    mloc = fmaxf(mloc, __shfl_xor(mloc, 16));
    mloc = fmaxf(mloc, __shfl_xor(mloc, 32));
    float mnew = fmaxf(m_run, mloc);
    float alpha = __expf(m_run - mnew);     // first iter: exp(-inf)=0
    m_run = mnew;
    float rs = 0.f;
#pragma unroll
    for (int kt = 0; kt < 4; kt++)
#pragma unroll
      for (int r = 0; r < 4; r++) {
        float p = __expf(ST[kt][r] - mnew);
        ST[kt][r] = p;
        rs += p;
      }
    rs += __shfl_xor(rs, 16);
    rs += __shfl_xor(rs, 32);
    l_run = l_run * alpha + rs;
#pragma unroll
    for (int dt = 0; dt < 4; dt++) O[dt] = O[dt] * alpha;

    // write P^T: row q=lc, keys kt*16+quad*4+reg (4 consecutive keys -> b64)
#pragma unroll
    for (int kt = 0; kt < 4; kt++) {
      bf16x4 pk;
#pragma unroll
      for (int r = 0; r < 4; r++) pk[r] = (bf16_t)ST[kt][r];
      *(bf16x4*)&Pt[wv][lc * 72 + kt * 16 + quad * 4] = pk;
    }
    __syncthreads();

    // O^T[d][q] += V^T · P^T
#pragma unroll
    for (int ks = 0; ks < 2; ks++) {
      bf16x8 pb = *(const bf16x8*)&Pt[wv][lc * 72 + ks * 32 + quad * 8];
#pragma unroll
      for (int dt = 0; dt < 4; dt++) {
        bf16x8 va = *(const bf16x8*)&Vt[(dt * 16 + lc) * 72 + ks * 32 + quad * 8];
        O[dt] = mfma16(va, pb, O[dt]);
      }
    }
  }

  // epilogue: O^T rows d = dt*16 + quad*4 + r, col q = lc
  float invl = 1.f / l_run;
  int rg = b * SQ_ + qb + wv * 16 + lc;
  float gv = gate_buf[rg] * invl;
  float* orow = out + (size_t)rg * HID_ + h * HD_;
#pragma unroll
  for (int dt = 0; dt < 4; dt++)
#pragma unroll
    for (int r = 0; r < 4; r++)
      orow[dt * 16 + quad * 4 + r] = O[dt][r] * gv;
}

// ---------------- loss reduction ----------------
__global__ __launch_bounds__(256) void k_loss(const float* __restrict__ lg,
                                              const float* __restrict__ vm,
                                              float* __restrict__ out_loss) {
  int t = threadIdx.x;
  float s = 0.f, cnt = 0.f;
  for (int i = t; i < B_ * SQ_; i += 256) {
    s += lg[i];
    cnt += (vm[i] > 0.5f) ? 0.f : 1.f;
  }
  __shared__ float sb[8];
  for (int o = 32; o; o >>= 1) { s += __shfl_xor(s, o); cnt += __shfl_xor(cnt, o); }
  if ((t & 63) == 0) { sb[t >> 6] = s; sb[4 + (t >> 6)] = cnt; }
  __syncthreads();
  if (t == 0) {
    s   = sb[0] + sb[1] + sb[2] + sb[3];
    cnt = sb[4] + sb[5] + sb[6] + sb[7];
    out_loss[0] = s / fmaxf(cnt, 1.f) * 0.05f;
  }
}

extern "C" void kernel_launch(void* const* d_in, const int* in_sizes, int n_in,
                              void* d_out, int out_size, void* d_ws, size_t ws_size,
                              hipStream_t stream) {
  (void)in_sizes; (void)n_in; (void)out_size; (void)ws_size;
  const float* hidden = (const float*)d_in[0];
  const float* sat    = (const float*)d_in[1];
  const float* sat_xy = (const float*)d_in[2];
  const float* bev_xy = (const float*)d_in[3];
  const float* plk    = (const float*)d_in[4];
  const float* vm     = (const float*)d_in[5];
  const float* Wq     = (const float*)d_in[6];
  const float* bq     = (const float*)d_in[7];
  const float* slg    = (const float*)d_in[8];
  const float* slb    = (const float*)d_in[9];
  const float* Wk     = (const float*)d_in[10];
  const float* bk     = (const float*)d_in[11];
  const float* Wv     = (const float*)d_in[12];
  const float* bv     = (const float*)d_in[13];
  const float* Wp1    = (const float*)d_in[14];
  const float* bp1    = (const float*)d_in[15];
  const float* Wp2    = (const float*)d_in[16];
  const float* bp2    = (const float*)d_in[17];
  const float* glg    = (const float*)d_in[18];
  const float* glb    = (const float*)d_in[19];
  const float* Wg     = (const float*)d_in[20];
  const float* bg     = (const float*)d_in[21];
  float* out = (float*)d_out;

  char* ws = (char*)d_ws;
  size_t off = 0;
  auto alloc = [&](size_t bytes) -> char* {
    char* p = ws + off;
    off += (bytes + 255) & ~(size_t)255;
    return p;
  };
  // region A: pf1, later reused for q_lin (both 16384x640 bf16)
  unsigned short* regA = (unsigned short*)alloc((size_t)16384 * 640 * 2);
  // region B: pf2, later reused for {kv_lin (4096x1280) + sn (4096x768)}
  char* regB = alloc((size_t)16384 * 640 * 2);
  unsigned short* pf1    = regA;
  unsigned short* q_lin  = regA;
  unsigned short* pf2    = (unsigned short*)regB;
  unsigned short* kv_lin = (unsigned short*)regB;
  unsigned short* sn     = (unsigned short*)(regB + (size_t)4096 * 1280 * 2);
  unsigned short* vT     = (unsigned short*)alloc((size_t)B_ * HID_ * SK_ * 2);
  unsigned short* wqT    = (unsigned short*)alloc((size_t)640 * 640 * 2);
  unsigned short* kvT    = (unsigned short*)alloc((size_t)1280 * 768 * 2);
  unsigned short* wp2T   = (unsigned short*)alloc((size_t)640 * 640 * 2);
  float* bias_kv  = (float*)alloc(1280 * 4);
  float* gate_buf = (float*)alloc(16384 * 4);
  float* lg_buf   = (float*)alloc(16384 * 4);

  // 1) weight prep
  k_transpose_w<<<(640 * 640 + 255) / 256, 256, 0, stream>>>(Wq, wqT, 640, 640);
  k_transpose_w<<<(640 * 768 + 255) / 256, 256, 0, stream>>>(Wk, kvT, 768, 640);
  k_transpose_w<<<(640 * 768 + 255) / 256, 256, 0, stream>>>(Wv, kvT + (size_t)640 * 768, 768, 640);
  k_transpose_w<<<(640 * 640 + 255) / 256, 256, 0, stream>>>(Wp2, wp2T, 640, 640);
  k_concat_bias<<<5, 256, 0, stream>>>(bk, bv, bias_kv);

  // 2) gate path: pf1 -> pf2 -> gate
  k_pf1<<<16384 * 640 / 256, 256, 0, stream>>>(plk, Wp1, bp1, pf1);
  {
    dim3 g(128, 5);
    k_gemm<false><<<g, 256, 0, stream>>>(pf1, wp2T, bp2, pf2, 16384, 640, 640);
  }
  k_gate<<<16384, 256, 0, stream>>>(hidden, pf2, glg, glb, Wg, bg, vm, gate_buf, lg_buf);

  // 3) sat path: LN -> fused K|V GEMM  (pf2 region now dead)
  k_satln<<<4096, 256, 0, stream>>>(sat, slg, slb, sn);
  {
    dim3 g(32, 10);
    k_gemm<false><<<g, 256, 0, stream>>>(sn, kvT, bias_kv, kv_lin, 4096, 1280, 768);
  }

  // 4) Q GEMM (pf1 region now dead -> q_lin), RoPE, V transpose
  {
    dim3 g(128, 5);
    k_gemm<true><<<g, 256, 0, stream>>>(hidden, wqT, bq, q_lin, 16384, 640, 640);
  }
  k_rope<<<16384 * NH_ * 32 / 256, 256, 0, stream>>>(q_lin, bev_xy, 16384, 640, 0.125f);
  k_rope<<<4096 * NH_ * 32 / 256, 256, 0, stream>>>(kv_lin, sat_xy, 4096, 1280, 1.0f);
  {
    dim3 g(SK_ / 64, HID_ / 64, B_);
    k_transpose_v<<<g, 256, 0, stream>>>(kv_lin, vT);
  }

  // 5) attention -> out, then loss
  {
    dim3 g(SQ_ / 64, B_ * NH_);
    k_attn<<<g, 256, 0, stream>>>(q_lin, kv_lin, vT, gate_buf, out);
  }
  k_loss<<<1, 256, 0, stream>>>(lg_buf, vm, out + (size_t)B_ * SQ_ * HID_);
}